// Round 6
// baseline (488.803 us; speedup 1.0000x reference)
//
#include <hip/hip_runtime.h>
#include <stdint.h>

typedef unsigned short u16;
typedef __attribute__((ext_vector_type(8))) short short8;
typedef __attribute__((ext_vector_type(4))) float f32x4;
typedef __attribute__((ext_vector_type(16))) float f32x16;
typedef __attribute__((ext_vector_type(4))) unsigned short u16x4;

__device__ __forceinline__ u16 f2bf(float f) {
  uint32_t u = __float_as_uint(f);
  return (u16)((u + 0x7FFFu + ((u >> 16) & 1u)) >> 16);
}

__device__ __forceinline__ void gl2lds16(const u16* g, u16* l) {
  __builtin_amdgcn_global_load_lds(
      (const __attribute__((address_space(1))) unsigned int*)g,
      (__attribute__((address_space(3))) unsigned int*)l, 16, 0, 0);
}

__device__ __forceinline__ float exp2fast(float x) {
#if __has_builtin(__builtin_amdgcn_exp2f)
  return __builtin_amdgcn_exp2f(x);
#else
  return exp2f(x);
#endif
}

__device__ __forceinline__ unsigned int cvtpk(float lo, float hi) {
  unsigned int r;
  asm("v_cvt_pk_bf16_f32 %0, %1, %2" : "=v"(r) : "v"(lo), "v"(hi));
  return r;
}

// cross-half (lane vs lane^32) combine helpers via permlane32_swap
__device__ __forceinline__ float halfmax(float x) {
  auto r = __builtin_amdgcn_permlane32_swap(__float_as_uint(x), __float_as_uint(x), false, false);
  return fmaxf(__uint_as_float(r[0]), __uint_as_float(r[1]));
}
__device__ __forceinline__ float halfadd(float x) {
  auto r = __builtin_amdgcn_permlane32_swap(__float_as_uint(x), __float_as_uint(x), false, false);
  return __uint_as_float(r[0]) + __uint_as_float(r[1]);
}

// ---------- convert + concat: kvin[b][t][e] bf16, t<2048 -> x, else latents ----------
__global__ __launch_bounds__(256) void conv_kvin(const float* __restrict__ x,
                                                 const float* __restrict__ lat,
                                                 u16* __restrict__ kvin) {
  const int64_t total8 = (int64_t)20480 * 1024 / 8;
  for (int64_t i = (int64_t)blockIdx.x * 256 + threadIdx.x; i < total8;
       i += (int64_t)gridDim.x * 256) {
    const int64_t e0 = i * 8;
    const int row = (int)(e0 >> 10);
    const int col = (int)(e0 & 1023);
    const int b = row / 2560;
    const int t = row - b * 2560;
    const float* src = (t < 2048)
        ? (x + ((int64_t)b * 2048 + t) * 1024 + col)
        : (lat + ((int64_t)b * 512 + (t - 2048)) * 1024 + col);
    const float4 v0 = *(const float4*)src;
    const float4 v1 = *(const float4*)(src + 4);
    union { u16 s[8]; short8 v; } pk;
    pk.s[0] = f2bf(v0.x); pk.s[1] = f2bf(v0.y); pk.s[2] = f2bf(v0.z); pk.s[3] = f2bf(v0.w);
    pk.s[4] = f2bf(v1.x); pk.s[5] = f2bf(v1.y); pk.s[6] = f2bf(v1.z); pk.s[7] = f2bf(v1.w);
    *(short8*)(kvin + e0) = pk.v;
  }
}

// ---------- mask -> additive bias over concatenated kv timeline ----------
__global__ __launch_bounds__(256) void prep_bias(const float* __restrict__ mask_x,
                                                 const float* __restrict__ mask_lat,
                                                 float* __restrict__ biasKV) {
  const int i = blockIdx.x * 256 + threadIdx.x;  // < 20480
  if (i >= 20480) return;
  const int b = i / 2560, t = i - b * 2560;
  const float m = (t < 2048) ? mask_x[b * 2048 + t] : mask_lat[b * 512 + t - 2048];
  biasKV[i] = (1.0f - m) * (-1.0e30f);
}

// ---------- transpose + convert weights: dst[n][k] = bf16(src[k][n]) ----------
__global__ __launch_bounds__(256) void convT(const float* __restrict__ src,
                                             u16* __restrict__ dst, int K, int N) {
  __shared__ float tile[32][33];
  const int kb = blockIdx.x * 32, nb = blockIdx.y * 32;
  const int tx = threadIdx.x & 31, ty = threadIdx.x >> 5;
  #pragma unroll
  for (int i = 0; i < 4; i++)
    tile[ty + i * 8][tx] = src[(int64_t)(kb + ty + i * 8) * N + nb + tx];
  __syncthreads();
  #pragma unroll
  for (int i = 0; i < 4; i++)
    dst[(int64_t)(nb + ty + i * 8) * K + kb + tx] = f2bf(tile[tx][ty + i * 8]);
}

// ---------- 128x128 bf16 MFMA GEMM, K=1024, B given as Bt[N][K] ----------
// MODE 0: q-GEMM   (A rows = latent part of kvin; out bf16 * 0.125*log2e for exp2-domain softmax)
// MODE 1: kv-GEMM  (out col<1024 -> kbuf row-major bf16; col>=1024 -> vT transposed bf16)
// MODE 2: out-GEMM (A already bf16 flat, out fp32)
template <int MODE>
__global__ __launch_bounds__(256) void gemm128(const u16* __restrict__ A0,
                                               const u16* __restrict__ Bt,
                                               void* __restrict__ C0,
                                               void* __restrict__ C1) {
  __shared__ u16 As[128 * 64];
  __shared__ u16 Bs[128 * 64];
  const int tid = threadIdx.x;
  const int lane = tid & 63, wave = tid >> 6;
  const int l16 = lane & 15, g4 = lane >> 4;
  const int bm = blockIdx.x, bn = blockIdx.y;

  const u16* Arow;
  if (MODE == 0) {
    const int b = bm >> 2;
    Arow = A0 + ((int64_t)b * 2560 + 2048 + (int64_t)(bm & 3) * 128) * 1024;
  } else {
    Arow = A0 + (int64_t)bm * 128 * 1024;
  }
  const u16* Brow = Bt + (int64_t)bn * 128 * 1024;

  const int wm = wave >> 1, wn = wave & 1;
  const int srow = lane >> 3;
  const int scol = (lane & 7) * 8;

  f32x4 acc[4][4];
  #pragma unroll
  for (int m = 0; m < 4; m++)
    #pragma unroll
    for (int n = 0; n < 4; n++)
      acc[m][n] = (f32x4){0.f, 0.f, 0.f, 0.f};

  for (int kt = 0; kt < 1024; kt += 64) {
    #pragma unroll
    for (int i = 0; i < 4; i++) {
      const int c = wave * 4 + i;
      gl2lds16(Arow + (int64_t)(c * 8 + srow) * 1024 + kt + scol, &As[c * 512]);
      gl2lds16(Brow + (int64_t)(c * 8 + srow) * 1024 + kt + scol, &Bs[c * 512]);
    }
    __syncthreads();
    #pragma unroll
    for (int kk = 0; kk < 2; kk++) {
      short8 af[4], bfr[4];
      #pragma unroll
      for (int m = 0; m < 4; m++)
        af[m] = *(const short8*)&As[(wm * 64 + m * 16 + l16) * 64 + kk * 32 + g4 * 8];
      #pragma unroll
      for (int n = 0; n < 4; n++)
        bfr[n] = *(const short8*)&Bs[(wn * 64 + n * 16 + l16) * 64 + kk * 32 + g4 * 8];
      #pragma unroll
      for (int m = 0; m < 4; m++)
        #pragma unroll
        for (int n = 0; n < 4; n++)
          acc[m][n] = __builtin_amdgcn_mfma_f32_16x16x32_bf16(af[m], bfr[n], acc[m][n], 0, 0, 0);
    }
    __syncthreads();
  }

  const int r0 = bm * 128 + wm * 64;
  const int c0 = bn * 128 + wn * 64;
  #pragma unroll
  for (int m = 0; m < 4; m++) {
    #pragma unroll
    for (int n = 0; n < 4; n++) {
      const int col = c0 + n * 16 + l16;
      if (MODE == 1 && col >= 1024) {
        const int rbase = r0 + m * 16 + g4 * 4;
        const int b = rbase / 2560;
        const int t = rbase - b * 2560;
        u16x4 vv;
        vv[0] = f2bf(acc[m][n][0]); vv[1] = f2bf(acc[m][n][1]);
        vv[2] = f2bf(acc[m][n][2]); vv[3] = f2bf(acc[m][n][3]);
        *(u16x4*)((u16*)C1 + ((int64_t)b * 1024 + (col - 1024)) * 2560 + t) = vv;
      } else {
        #pragma unroll
        for (int j = 0; j < 4; j++) {
          const int row = r0 + m * 16 + g4 * 4 + j;
          const float v = acc[m][n][j];
          if (MODE == 2)      ((float*)C0)[(int64_t)row * 1024 + col] = v;
          else if (MODE == 0) ((u16*)C0)[(int64_t)row * 1024 + col] = f2bf(v * 0.18033688f);
          else                ((u16*)C0)[(int64_t)row * 1024 + col] = f2bf(v);
        }
      }
    }
  }
}

// ---------- flash attention v4: 4 waves split the KV timeline, symmetric LDS merge ----------
// Block = 32 q-rows of one (b,h); wave w handles t in [w*640, w*640+640).
// Inner loop identical to the verified attn2. Merge: every wave rescales to the
// block max and writes its own slot; wave 0 sums all 4 slots (two yacc phases
// reuse one padded buffer). No read-modify-write slot aliasing.
__global__ __launch_bounds__(256, 4) void attn4(const u16* __restrict__ q,
                                                const u16* __restrict__ kbuf,
                                                const u16* __restrict__ vT,
                                                const float* __restrict__ biasKV,
                                                u16* __restrict__ y) {
  __shared__ float mArr[4][32];
  __shared__ float lArr[4][64];
  __shared__ float yH[4][64][17];  // stride 17 (odd) -> conflict-free column reads

  // bijective XCD swizzle over 2048 blocks: 256 consecutive logical ids per XCD
  const int id = blockIdx.x;                 // 0..2047
  const int wgid = (id & 7) * 256 + (id >> 3);
  const int bh = wgid >> 4;                  // 0..127
  const int qb = wgid & 15;                  // 0..15
  const int b = bh >> 4, h = bh & 15;
  const int lane = threadIdx.x & 63, wave = threadIdx.x >> 6;
  const int l32 = lane & 31, hi = lane >> 5;
  const int q0 = qb * 32;

  // Q^T B-fragments: col q = l32, d = c*16 + hi*8 + j   (q pre-scaled by 0.125*log2e)
  short8 qf[4];
  const u16* qrow = q + ((int64_t)(b * 512 + q0 + l32)) * 1024 + h * 64;
  #pragma unroll
  for (int c = 0; c < 4; c++)
    qf[c] = *(const short8*)(qrow + c * 16 + hi * 8);

  float mrun = -3.0e38f, lsum = 0.f;
  f32x16 yacc0, yacc1;
  #pragma unroll
  for (int i = 0; i < 16; i++) { yacc0[i] = 0.f; yacc1[i] = 0.f; }

  const u16* kbase = kbuf + ((int64_t)(b * 2560 + l32)) * 1024 + h * 64;
  const u16* vbase = vT + ((int64_t)(b * 1024 + h * 64 + l32)) * 2560;
  const float* bbase = biasKV + b * 2560;

  const int tbeg = wave * 640, tend = tbeg + 640;
  for (int t0 = tbeg; t0 < tend; t0 += 32) {
    // K A-fragments: row t = t0 + l32, d = c*16 + hi*8 + j
    short8 kf[4];
    #pragma unroll
    for (int c = 0; c < 4; c++)
      kf[c] = *(const short8*)(kbase + (int64_t)t0 * 1024 + c * 16 + hi * 8);
    // V^T A-fragments: row d = db*32 + l32, t = t0 + ks*16 + hi*8 + j
    short8 vf[2][2];
    #pragma unroll
    for (int db = 0; db < 2; db++)
      #pragma unroll
      for (int ks = 0; ks < 2; ks++)
        vf[db][ks] = *(const short8*)(vbase + (int64_t)db * 32 * 2560 + t0 + ks * 16 + hi * 8);
    // mask bias, float4 per reg-group g: t = t0 + g*8 + 4*hi + (r&3)
    float4 bb[4];
    #pragma unroll
    for (int g = 0; g < 4; g++)
      bb[g] = *(const float4*)(bbase + t0 + g * 8 + hi * 4);

    // S^T[k][q] = sum_d K[k][d] * Q^T[d][q]
    f32x16 S;
    #pragma unroll
    for (int i = 0; i < 16; i++) S[i] = 0.f;
    #pragma unroll
    for (int c = 0; c < 4; c++)
      S = __builtin_amdgcn_mfma_f32_32x32x16_bf16(kf[c], qf[c], S, 0, 0, 0);

    float t[16];
    #pragma unroll
    for (int r = 0; r < 16; r++) t[r] = S[r] + bb[r >> 2][r & 3];

    // row max: in-register tree + one cross-half swap
    float m01 = fmaxf(t[0], t[1]),  m23 = fmaxf(t[2], t[3]);
    float m45 = fmaxf(t[4], t[5]),  m67 = fmaxf(t[6], t[7]);
    float m89 = fmaxf(t[8], t[9]),  mab = fmaxf(t[10], t[11]);
    float mcd = fmaxf(t[12], t[13]), mef = fmaxf(t[14], t[15]);
    float tm = fmaxf(fmaxf(fmaxf(m01, m23), fmaxf(m45, m67)),
                     fmaxf(fmaxf(m89, mab), fmaxf(mcd, mef)));
    tm = halfmax(tm);

    // defer-max: rescale only when the running max grew past threshold (log2 units)
    if (__any(tm > mrun + 8.f)) {
      const float nm = fmaxf(mrun, tm);
      const float alpha = exp2fast(mrun - nm);
      mrun = nm;
      lsum *= alpha;
      #pragma unroll
      for (int i = 0; i < 16; i++) { yacc0[i] *= alpha; yacc1[i] *= alpha; }
    }

    float p[16];
    #pragma unroll
    for (int r = 0; r < 16; r++) p[r] = exp2fast(t[r] - mrun);

    float ps = ((p[0] + p[1]) + (p[2] + p[3])) + ((p[4] + p[5]) + (p[6] + p[7]));
    ps += ((p[8] + p[9]) + (p[10] + p[11])) + ((p[12] + p[13]) + (p[14] + p[15]));
    lsum += halfadd(ps);

    // P^T B-fragments via cvt_pk + permlane32_swap (T12): 8 cvt + 4 swaps -> 8 words
    union PA { unsigned int w[4]; short8 v; } pa0, pa1;
    {
      auto r0 = __builtin_amdgcn_permlane32_swap(cvtpk(p[0], p[1]), cvtpk(p[4], p[5]), false, false);
      pa0.w[0] = r0[0]; pa0.w[2] = r0[1];
      auto r1 = __builtin_amdgcn_permlane32_swap(cvtpk(p[2], p[3]), cvtpk(p[6], p[7]), false, false);
      pa0.w[1] = r1[0]; pa0.w[3] = r1[1];
      auto r2 = __builtin_amdgcn_permlane32_swap(cvtpk(p[8], p[9]), cvtpk(p[12], p[13]), false, false);
      pa1.w[0] = r2[0]; pa1.w[2] = r2[1];
      auto r3 = __builtin_amdgcn_permlane32_swap(cvtpk(p[10], p[11]), cvtpk(p[14], p[15]), false, false);
      pa1.w[1] = r3[0]; pa1.w[3] = r3[1];
    }

    // Y^T[d][q] += V^T[d][k] * P^T[k][q]
    yacc0 = __builtin_amdgcn_mfma_f32_32x32x16_bf16(vf[0][0], pa0.v, yacc0, 0, 0, 0);
    yacc0 = __builtin_amdgcn_mfma_f32_32x32x16_bf16(vf[0][1], pa1.v, yacc0, 0, 0, 0);
    yacc1 = __builtin_amdgcn_mfma_f32_32x32x16_bf16(vf[1][0], pa0.v, yacc1, 0, 0, 0);
    yacc1 = __builtin_amdgcn_mfma_f32_32x32x16_bf16(vf[1][1], pa1.v, yacc1, 0, 0, 0);
  }

  // ---- symmetric flash merge across the 4 waves ----
  if (hi == 0) mArr[wave][l32] = mrun;
  __syncthreads();
  {
    const float M = fmaxf(fmaxf(mArr[0][l32], mArr[1][l32]),
                          fmaxf(mArr[2][l32], mArr[3][l32]));
    const float alpha = exp2fast(mrun - M);
    lsum *= alpha;
    #pragma unroll
    for (int i = 0; i < 16; i++) { yacc0[i] *= alpha; yacc1[i] *= alpha; }
  }
  lArr[wave][lane] = lsum;
  #pragma unroll
  for (int i = 0; i < 16; i++) yH[wave][lane][i] = yacc0[i];
  __syncthreads();

  float ltot = 0.f;
  f32x16 y0t, y1t;
  #pragma unroll
  for (int i = 0; i < 16; i++) { y0t[i] = 0.f; y1t[i] = 0.f; }
  if (wave == 0) {
    ltot = (lArr[0][lane] + lArr[1][lane]) + (lArr[2][lane] + lArr[3][lane]);
    #pragma unroll
    for (int i = 0; i < 16; i++)
      y0t[i] = (yH[0][lane][i] + yH[1][lane][i]) + (yH[2][lane][i] + yH[3][lane][i]);
  }
  __syncthreads();  // protect yH before reuse
  #pragma unroll
  for (int i = 0; i < 16; i++) yH[wave][lane][i] = yacc1[i];
  __syncthreads();
  if (wave == 0) {
    #pragma unroll
    for (int i = 0; i < 16; i++)
      y1t[i] = (yH[0][lane][i] + yH[1][lane][i]) + (yH[2][lane][i] + yH[3][lane][i]);
    const float inv = 1.0f / ltot;
    u16* yr = y + ((int64_t)(b * 512 + q0 + l32)) * 1024 + h * 64;
    #pragma unroll
    for (int g = 0; g < 4; g++) {
      u16x4 o0, o1;
      #pragma unroll
      for (int j = 0; j < 4; j++) {
        o0[j] = f2bf(y0t[g * 4 + j] * inv);
        o1[j] = f2bf(y1t[g * 4 + j] * inv);
      }
      *(u16x4*)(yr + g * 8 + hi * 4) = o0;
      *(u16x4*)(yr + 32 + g * 8 + hi * 4) = o1;
    }
  }
}

extern "C" void kernel_launch(void* const* d_in, const int* in_sizes, int n_in,
                              void* d_out, int out_size, void* d_ws, size_t ws_size,
                              hipStream_t stream) {
  const float* x        = (const float*)d_in[0];
  const float* lat      = (const float*)d_in[1];
  const float* mask_x   = (const float*)d_in[2];
  const float* mask_lat = (const float*)d_in[3];
  const float* Wq       = (const float*)d_in[4];
  const float* Wkv      = (const float*)d_in[5];
  const float* Wp       = (const float*)d_in[6];

  // workspace carve (bf16 = u16), total ~143 MB
  u16* kvin = (u16*)d_ws;                         // [8][2560][1024]
  u16* WqT  = kvin + (int64_t)20480 * 1024;       // [1024][1024]
  u16* WkvT = WqT  + (int64_t)1024 * 1024;        // [2048][1024]
  u16* WpT  = WkvT + (int64_t)2048 * 1024;        // [1024][1024]
  u16* qb   = WpT  + (int64_t)1024 * 1024;        // [4096][1024]
  u16* kb   = qb   + (int64_t)4096 * 1024;        // [8*2560][1024]
  u16* vT   = kb   + (int64_t)20480 * 1024;       // [8*1024][2560]
  float* biasKV = (float*)(vT + (int64_t)20480 * 1024);  // [8][2560]
  u16* yb   = kvin;                               // reuse kvin after GEMMs

  conv_kvin<<<2560, 256, 0, stream>>>(x, lat, kvin);
  prep_bias<<<80, 256, 0, stream>>>(mask_x, mask_lat, biasKV);
  convT<<<dim3(32, 32), 256, 0, stream>>>(Wq, WqT, 1024, 1024);
  convT<<<dim3(32, 64), 256, 0, stream>>>(Wkv, WkvT, 1024, 2048);
  convT<<<dim3(32, 32), 256, 0, stream>>>(Wp, WpT, 1024, 1024);

  gemm128<0><<<dim3(32, 8), 256, 0, stream>>>(kvin, WqT, qb, nullptr);
  gemm128<1><<<dim3(160, 16), 256, 0, stream>>>(kvin, WkvT, kb, vT);
  attn4<<<2048, 256, 0, stream>>>(qb, kb, vT, biasKV, yb);
  gemm128<2><<<dim3(32, 8), 256, 0, stream>>>(yb, WpT, d_out, nullptr);
}

// Round 7
// 398.563 us; speedup vs baseline: 1.2264x; 1.2264x over previous
//
#include <hip/hip_runtime.h>
#include <stdint.h>

typedef unsigned short u16;
typedef __attribute__((ext_vector_type(8))) short short8;
typedef __attribute__((ext_vector_type(4))) float f32x4;
typedef __attribute__((ext_vector_type(16))) float f32x16;
typedef __attribute__((ext_vector_type(4))) unsigned short u16x4;

__device__ __forceinline__ u16 f2bf(float f) {
  uint32_t u = __float_as_uint(f);
  return (u16)((u + 0x7FFFu + ((u >> 16) & 1u)) >> 16);
}

__device__ __forceinline__ void gl2lds16(const u16* g, u16* l) {
  __builtin_amdgcn_global_load_lds(
      (const __attribute__((address_space(1))) unsigned int*)g,
      (__attribute__((address_space(3))) unsigned int*)l, 16, 0, 0);
}

__device__ __forceinline__ float exp2fast(float x) {
#if __has_builtin(__builtin_amdgcn_exp2f)
  return __builtin_amdgcn_exp2f(x);
#else
  return exp2f(x);
#endif
}

__device__ __forceinline__ unsigned int cvtpk(float lo, float hi) {
  unsigned int r;
  asm("v_cvt_pk_bf16_f32 %0, %1, %2" : "=v"(r) : "v"(lo), "v"(hi));
  return r;
}

// cross-half (lane vs lane^32) combine helpers via permlane32_swap
__device__ __forceinline__ float halfmax(float x) {
  auto r = __builtin_amdgcn_permlane32_swap(__float_as_uint(x), __float_as_uint(x), false, false);
  return fmaxf(__uint_as_float(r[0]), __uint_as_float(r[1]));
}
__device__ __forceinline__ float halfadd(float x) {
  auto r = __builtin_amdgcn_permlane32_swap(__float_as_uint(x), __float_as_uint(x), false, false);
  return __uint_as_float(r[0]) + __uint_as_float(r[1]);
}

// ---------- convert + concat: kvin[b][t][e] bf16, t<2048 -> x, else latents ----------
__global__ __launch_bounds__(256) void conv_kvin(const float* __restrict__ x,
                                                 const float* __restrict__ lat,
                                                 u16* __restrict__ kvin) {
  const int64_t total8 = (int64_t)20480 * 1024 / 8;
  for (int64_t i = (int64_t)blockIdx.x * 256 + threadIdx.x; i < total8;
       i += (int64_t)gridDim.x * 256) {
    const int64_t e0 = i * 8;
    const int row = (int)(e0 >> 10);
    const int col = (int)(e0 & 1023);
    const int b = row / 2560;
    const int t = row - b * 2560;
    const float* src = (t < 2048)
        ? (x + ((int64_t)b * 2048 + t) * 1024 + col)
        : (lat + ((int64_t)b * 512 + (t - 2048)) * 1024 + col);
    const float4 v0 = *(const float4*)src;
    const float4 v1 = *(const float4*)(src + 4);
    union { u16 s[8]; short8 v; } pk;
    pk.s[0] = f2bf(v0.x); pk.s[1] = f2bf(v0.y); pk.s[2] = f2bf(v0.z); pk.s[3] = f2bf(v0.w);
    pk.s[4] = f2bf(v1.x); pk.s[5] = f2bf(v1.y); pk.s[6] = f2bf(v1.z); pk.s[7] = f2bf(v1.w);
    *(short8*)(kvin + e0) = pk.v;
  }
}

// ---------- mask -> additive bias over concatenated kv timeline ----------
__global__ __launch_bounds__(256) void prep_bias(const float* __restrict__ mask_x,
                                                 const float* __restrict__ mask_lat,
                                                 float* __restrict__ biasKV) {
  const int i = blockIdx.x * 256 + threadIdx.x;  // < 20480
  if (i >= 20480) return;
  const int b = i / 2560, t = i - b * 2560;
  const float m = (t < 2048) ? mask_x[b * 2048 + t] : mask_lat[b * 512 + t - 2048];
  biasKV[i] = (1.0f - m) * (-1.0e30f);
}

// ---------- transpose + convert weights: dst[n][k] = bf16(src[k][n]) ----------
__global__ __launch_bounds__(256) void convT(const float* __restrict__ src,
                                             u16* __restrict__ dst, int K, int N) {
  __shared__ float tile[32][33];
  const int kb = blockIdx.x * 32, nb = blockIdx.y * 32;
  const int tx = threadIdx.x & 31, ty = threadIdx.x >> 5;
  #pragma unroll
  for (int i = 0; i < 4; i++)
    tile[ty + i * 8][tx] = src[(int64_t)(kb + ty + i * 8) * N + nb + tx];
  __syncthreads();
  #pragma unroll
  for (int i = 0; i < 4; i++)
    dst[(int64_t)(nb + ty + i * 8) * K + kb + tx] = f2bf(tile[tx][ty + i * 8]);
}

// ---------- 128x128 bf16 MFMA GEMM, K=1024, B given as Bt[N][K] ----------
// MODE 0: q-GEMM   (A rows = latent part of kvin; out bf16 * 0.125*log2e for exp2-domain softmax)
// MODE 1: kv-GEMM  (out col<1024 -> kbuf row-major bf16; col>=1024 -> vT transposed bf16)
// MODE 2: out-GEMM (A already bf16 flat, out fp32)
template <int MODE>
__global__ __launch_bounds__(256) void gemm128(const u16* __restrict__ A0,
                                               const u16* __restrict__ Bt,
                                               void* __restrict__ C0,
                                               void* __restrict__ C1) {
  __shared__ u16 As[128 * 64];
  __shared__ u16 Bs[128 * 64];
  const int tid = threadIdx.x;
  const int lane = tid & 63, wave = tid >> 6;
  const int l16 = lane & 15, g4 = lane >> 4;
  const int bm = blockIdx.x, bn = blockIdx.y;

  const u16* Arow;
  if (MODE == 0) {
    const int b = bm >> 2;
    Arow = A0 + ((int64_t)b * 2560 + 2048 + (int64_t)(bm & 3) * 128) * 1024;
  } else {
    Arow = A0 + (int64_t)bm * 128 * 1024;
  }
  const u16* Brow = Bt + (int64_t)bn * 128 * 1024;

  const int wm = wave >> 1, wn = wave & 1;
  const int srow = lane >> 3;
  const int scol = (lane & 7) * 8;

  f32x4 acc[4][4];
  #pragma unroll
  for (int m = 0; m < 4; m++)
    #pragma unroll
    for (int n = 0; n < 4; n++)
      acc[m][n] = (f32x4){0.f, 0.f, 0.f, 0.f};

  for (int kt = 0; kt < 1024; kt += 64) {
    #pragma unroll
    for (int i = 0; i < 4; i++) {
      const int c = wave * 4 + i;
      gl2lds16(Arow + (int64_t)(c * 8 + srow) * 1024 + kt + scol, &As[c * 512]);
      gl2lds16(Brow + (int64_t)(c * 8 + srow) * 1024 + kt + scol, &Bs[c * 512]);
    }
    __syncthreads();
    #pragma unroll
    for (int kk = 0; kk < 2; kk++) {
      short8 af[4], bfr[4];
      #pragma unroll
      for (int m = 0; m < 4; m++)
        af[m] = *(const short8*)&As[(wm * 64 + m * 16 + l16) * 64 + kk * 32 + g4 * 8];
      #pragma unroll
      for (int n = 0; n < 4; n++)
        bfr[n] = *(const short8*)&Bs[(wn * 64 + n * 16 + l16) * 64 + kk * 32 + g4 * 8];
      #pragma unroll
      for (int m = 0; m < 4; m++)
        #pragma unroll
        for (int n = 0; n < 4; n++)
          acc[m][n] = __builtin_amdgcn_mfma_f32_16x16x32_bf16(af[m], bfr[n], acc[m][n], 0, 0, 0);
    }
    __syncthreads();
  }

  const int r0 = bm * 128 + wm * 64;
  const int c0 = bn * 128 + wn * 64;
  #pragma unroll
  for (int m = 0; m < 4; m++) {
    #pragma unroll
    for (int n = 0; n < 4; n++) {
      const int col = c0 + n * 16 + l16;
      if (MODE == 1 && col >= 1024) {
        const int rbase = r0 + m * 16 + g4 * 4;
        const int b = rbase / 2560;
        const int t = rbase - b * 2560;
        u16x4 vv;
        vv[0] = f2bf(acc[m][n][0]); vv[1] = f2bf(acc[m][n][1]);
        vv[2] = f2bf(acc[m][n][2]); vv[3] = f2bf(acc[m][n][3]);
        *(u16x4*)((u16*)C1 + ((int64_t)b * 1024 + (col - 1024)) * 2560 + t) = vv;
      } else {
        #pragma unroll
        for (int j = 0; j < 4; j++) {
          const int row = r0 + m * 16 + g4 * 4 + j;
          const float v = acc[m][n][j];
          if (MODE == 2)      ((float*)C0)[(int64_t)row * 1024 + col] = v;
          else if (MODE == 0) ((u16*)C0)[(int64_t)row * 1024 + col] = f2bf(v * 0.18033688f);
          else                ((u16*)C0)[(int64_t)row * 1024 + col] = f2bf(v);
        }
      }
    }
  }
}

// ---------- flash attention v5: block = 128 q-rows, K/V LDS-staged (coalesced + swizzled) ----------
// 4 waves x 32 q-rows each; all waves share double-buffered K/V tiles (64 kv-rows x 64d).
// Staging: linear LDS dest via global_load_lds, INVERSE-swizzled global source; reads apply the
// same slot XOR (s ^ (row&7)) -> <=4-way bank aliasing. One barrier per tile. No merge phase.
__global__ __launch_bounds__(256, 2) void attn5(const u16* __restrict__ q,
                                                const u16* __restrict__ kbuf,
                                                const u16* __restrict__ vT,
                                                const float* __restrict__ biasKV,
                                                u16* __restrict__ y) {
  __shared__ u16 Klds[2][64][64];  // [buf][t-row][d], 8KB each
  __shared__ u16 Vlds[2][64][64];  // [buf][d-row][t], 8KB each

  // bijective XCD swizzle over 512 blocks: same (b,h) -> same XCD
  const int id = blockIdx.x;                // 0..511
  const int xcd = id & 7, rest = id >> 3;   // rest 0..63
  const int bh = xcd * 16 + (rest >> 2);    // 0..127
  const int qb = rest & 3;                  // 0..3
  const int b = bh >> 4, h = bh & 15;
  const int lane = threadIdx.x & 63, wave = threadIdx.x >> 6;
  const int l32 = lane & 31, hi = lane >> 5;
  const int q0 = qb * 128 + wave * 32;

  const u16* kg = kbuf + (int64_t)(b * 2560) * 1024 + h * 64;  // row t stride 1024
  const u16* vg = vT + ((int64_t)(b * 1024 + h * 64)) * 2560;  // row d stride 2560
  const float* bbase = biasKV + b * 2560;

  // Q^T B-fragments: col q = l32, d = c*16 + hi*8 + j (scattered, loaded once)
  short8 qf[4];
  const u16* qrow = q + ((int64_t)(b * 512 + q0 + l32)) * 1024 + h * 64;
  #pragma unroll
  for (int c = 0; c < 4; c++)
    qf[c] = *(const short8*)(qrow + c * 16 + hi * 8);

  float mrun = -3.0e38f, lsum = 0.f;
  f32x16 yacc0, yacc1;
  #pragma unroll
  for (int i = 0; i < 16; i++) { yacc0[i] = 0.f; yacc1[i] = 0.f; }

  const int sr = lane >> 3;  // 0..7: row within an 8-row staging chunk
  const int ss = lane & 7;   // 0..7: 16B slot within a 128B row
  const int swslot = (ss ^ sr) * 8;  // inverse-swizzled source offset (u16)

  // prologue: stage tile 0 into buf 0
  #pragma unroll
  for (int j = 0; j < 2; j++) {
    const int r = wave * 16 + j * 8 + sr;
    gl2lds16(kg + (int64_t)r * 1024 + swslot, &Klds[0][wave * 16 + j * 8][0]);
    gl2lds16(vg + (int64_t)r * 2560 + swslot, &Vlds[0][wave * 16 + j * 8][0]);
  }
  __syncthreads();

  int cur = 0;
  for (int tile = 0; tile < 40; ++tile) {
    const int T0 = tile * 64;
    if (tile + 1 < 40) {  // stage next tile into the other buffer (drained at the barrier)
      const int nb = cur ^ 1, T1 = T0 + 64;
      #pragma unroll
      for (int j = 0; j < 2; j++) {
        const int r = wave * 16 + j * 8 + sr;
        gl2lds16(kg + (int64_t)(T1 + r) * 1024 + swslot, &Klds[nb][wave * 16 + j * 8][0]);
        gl2lds16(vg + (int64_t)r * 2560 + T1 + swslot, &Vlds[nb][wave * 16 + j * 8][0]);
      }
    }

    #pragma unroll
    for (int ht = 0; ht < 2; ++ht) {
      const int t0h = T0 + ht * 32;
      // K A-fragments from LDS: row = ht*32 + l32, slot (c*2+hi) ^ (l32&7)
      short8 kf[4];
      #pragma unroll
      for (int c = 0; c < 4; c++)
        kf[c] = *(const short8*)&Klds[cur][ht * 32 + l32][((c * 2 + hi) ^ (l32 & 7)) * 8];
      // V^T A-fragments from LDS: d-row = db*32 + l32, slot (ht*4+ks*2+hi) ^ (l32&7)
      short8 vf[2][2];
      #pragma unroll
      for (int db = 0; db < 2; db++)
        #pragma unroll
        for (int ks = 0; ks < 2; ks++)
          vf[db][ks] = *(const short8*)&Vlds[cur][db * 32 + l32]
                                            [((ht * 4 + ks * 2 + hi) ^ (l32 & 7)) * 8];
      // mask bias, float4 per reg-group g: t = t0h + g*8 + 4*hi + (r&3)
      float4 bb[4];
      #pragma unroll
      for (int g = 0; g < 4; g++)
        bb[g] = *(const float4*)(bbase + t0h + g * 8 + hi * 4);

      // S^T[k][q] = sum_d K[k][d] * Q^T[d][q]
      f32x16 S;
      #pragma unroll
      for (int i = 0; i < 16; i++) S[i] = 0.f;
      #pragma unroll
      for (int c = 0; c < 4; c++)
        S = __builtin_amdgcn_mfma_f32_32x32x16_bf16(kf[c], qf[c], S, 0, 0, 0);

      float t[16];
      #pragma unroll
      for (int r = 0; r < 16; r++) t[r] = S[r] + bb[r >> 2][r & 3];

      // row max: in-register tree + one cross-half swap
      float m01 = fmaxf(t[0], t[1]),  m23 = fmaxf(t[2], t[3]);
      float m45 = fmaxf(t[4], t[5]),  m67 = fmaxf(t[6], t[7]);
      float m89 = fmaxf(t[8], t[9]),  mab = fmaxf(t[10], t[11]);
      float mcd = fmaxf(t[12], t[13]), mef = fmaxf(t[14], t[15]);
      float tm = fmaxf(fmaxf(fmaxf(m01, m23), fmaxf(m45, m67)),
                       fmaxf(fmaxf(m89, mab), fmaxf(mcd, mef)));
      tm = halfmax(tm);

      // defer-max: rescale only when the running max grew past threshold (log2 units)
      if (__any(tm > mrun + 8.f)) {
        const float nm = fmaxf(mrun, tm);
        const float alpha = exp2fast(mrun - nm);
        mrun = nm;
        lsum *= alpha;
        #pragma unroll
        for (int i = 0; i < 16; i++) { yacc0[i] *= alpha; yacc1[i] *= alpha; }
      }

      float p[16];
      #pragma unroll
      for (int r = 0; r < 16; r++) p[r] = exp2fast(t[r] - mrun);

      float ps = ((p[0] + p[1]) + (p[2] + p[3])) + ((p[4] + p[5]) + (p[6] + p[7]));
      ps += ((p[8] + p[9]) + (p[10] + p[11])) + ((p[12] + p[13]) + (p[14] + p[15]));
      lsum += halfadd(ps);

      // P^T B-fragments via cvt_pk + permlane32_swap (T12)
      union PA { unsigned int w[4]; short8 v; } pa0, pa1;
      {
        auto r0 = __builtin_amdgcn_permlane32_swap(cvtpk(p[0], p[1]), cvtpk(p[4], p[5]), false, false);
        pa0.w[0] = r0[0]; pa0.w[2] = r0[1];
        auto r1 = __builtin_amdgcn_permlane32_swap(cvtpk(p[2], p[3]), cvtpk(p[6], p[7]), false, false);
        pa0.w[1] = r1[0]; pa0.w[3] = r1[1];
        auto r2 = __builtin_amdgcn_permlane32_swap(cvtpk(p[8], p[9]), cvtpk(p[12], p[13]), false, false);
        pa1.w[0] = r2[0]; pa1.w[2] = r2[1];
        auto r3 = __builtin_amdgcn_permlane32_swap(cvtpk(p[10], p[11]), cvtpk(p[14], p[15]), false, false);
        pa1.w[1] = r3[0]; pa1.w[3] = r3[1];
      }

      // Y^T[d][q] += V^T[d][k] * P^T[k][q]
      yacc0 = __builtin_amdgcn_mfma_f32_32x32x16_bf16(vf[0][0], pa0.v, yacc0, 0, 0, 0);
      yacc0 = __builtin_amdgcn_mfma_f32_32x32x16_bf16(vf[0][1], pa1.v, yacc0, 0, 0, 0);
      yacc1 = __builtin_amdgcn_mfma_f32_32x32x16_bf16(vf[1][0], pa0.v, yacc1, 0, 0, 0);
      yacc1 = __builtin_amdgcn_mfma_f32_32x32x16_bf16(vf[1][1], pa1.v, yacc1, 0, 0, 0);
    }

    __syncthreads();  // drains staging vmcnt; protects cur from overwrite next iter
    cur ^= 1;
  }

  const float inv = 1.0f / lsum;
  u16* yr = y + ((int64_t)(b * 512 + q0 + l32)) * 1024 + h * 64;
  #pragma unroll
  for (int g = 0; g < 4; g++) {
    u16x4 o0, o1;
    #pragma unroll
    for (int j = 0; j < 4; j++) {
      o0[j] = f2bf(yacc0[g * 4 + j] * inv);
      o1[j] = f2bf(yacc1[g * 4 + j] * inv);
    }
    *(u16x4*)(yr + g * 8 + hi * 4) = o0;
    *(u16x4*)(yr + 32 + g * 8 + hi * 4) = o1;
  }
}

extern "C" void kernel_launch(void* const* d_in, const int* in_sizes, int n_in,
                              void* d_out, int out_size, void* d_ws, size_t ws_size,
                              hipStream_t stream) {
  const float* x        = (const float*)d_in[0];
  const float* lat      = (const float*)d_in[1];
  const float* mask_x   = (const float*)d_in[2];
  const float* mask_lat = (const float*)d_in[3];
  const float* Wq       = (const float*)d_in[4];
  const float* Wkv      = (const float*)d_in[5];
  const float* Wp       = (const float*)d_in[6];

  // workspace carve (bf16 = u16), total ~143 MB
  u16* kvin = (u16*)d_ws;                         // [8][2560][1024]
  u16* WqT  = kvin + (int64_t)20480 * 1024;       // [1024][1024]
  u16* WkvT = WqT  + (int64_t)1024 * 1024;        // [2048][1024]
  u16* WpT  = WkvT + (int64_t)2048 * 1024;        // [1024][1024]
  u16* qb   = WpT  + (int64_t)1024 * 1024;        // [4096][1024]
  u16* kb   = qb   + (int64_t)4096 * 1024;        // [8*2560][1024]
  u16* vT   = kb   + (int64_t)20480 * 1024;       // [8*1024][2560]
  float* biasKV = (float*)(vT + (int64_t)20480 * 1024);  // [8][2560]
  u16* yb   = kvin;                               // reuse kvin after GEMMs

  conv_kvin<<<2560, 256, 0, stream>>>(x, lat, kvin);
  prep_bias<<<80, 256, 0, stream>>>(mask_x, mask_lat, biasKV);
  convT<<<dim3(32, 32), 256, 0, stream>>>(Wq, WqT, 1024, 1024);
  convT<<<dim3(32, 64), 256, 0, stream>>>(Wkv, WkvT, 1024, 2048);
  convT<<<dim3(32, 32), 256, 0, stream>>>(Wp, WpT, 1024, 1024);

  gemm128<0><<<dim3(32, 8), 256, 0, stream>>>(kvin, WqT, qb, nullptr);
  gemm128<1><<<dim3(160, 16), 256, 0, stream>>>(kvin, WkvT, kb, vT);
  attn5<<<512, 256, 0, stream>>>(qb, kb, vT, biasKV, yb);
  gemm128<2><<<dim3(32, 8), 256, 0, stream>>>(yb, WpT, d_out, nullptr);
}

// Round 8
// 365.240 us; speedup vs baseline: 1.3383x; 1.0912x over previous
//
#include <hip/hip_runtime.h>
#include <stdint.h>

typedef unsigned short u16;
typedef __attribute__((ext_vector_type(8))) short short8;
typedef __attribute__((ext_vector_type(4))) float f32x4;
typedef __attribute__((ext_vector_type(16))) float f32x16;
typedef __attribute__((ext_vector_type(4))) unsigned short u16x4;

__device__ __forceinline__ u16 f2bf(float f) {
  uint32_t u = __float_as_uint(f);
  return (u16)((u + 0x7FFFu + ((u >> 16) & 1u)) >> 16);
}

__device__ __forceinline__ void gl2lds16(const u16* g, u16* l) {
  __builtin_amdgcn_global_load_lds(
      (const __attribute__((address_space(1))) unsigned int*)g,
      (__attribute__((address_space(3))) unsigned int*)l, 16, 0, 0);
}

__device__ __forceinline__ float exp2fast(float x) {
#if __has_builtin(__builtin_amdgcn_exp2f)
  return __builtin_amdgcn_exp2f(x);
#else
  return exp2f(x);
#endif
}

__device__ __forceinline__ unsigned int cvtpk(float lo, float hi) {
  unsigned int r;
  asm("v_cvt_pk_bf16_f32 %0, %1, %2" : "=v"(r) : "v"(lo), "v"(hi));
  return r;
}

// cross-half (lane vs lane^32) combine helpers via permlane32_swap
__device__ __forceinline__ float halfmax(float x) {
  auto r = __builtin_amdgcn_permlane32_swap(__float_as_uint(x), __float_as_uint(x), false, false);
  return fmaxf(__uint_as_float(r[0]), __uint_as_float(r[1]));
}
__device__ __forceinline__ float halfadd(float x) {
  auto r = __builtin_amdgcn_permlane32_swap(__float_as_uint(x), __float_as_uint(x), false, false);
  return __uint_as_float(r[0]) + __uint_as_float(r[1]);
}

// ---------- convert + concat: kvin[b][t][e] bf16, t<2048 -> x, else latents ----------
__global__ __launch_bounds__(256) void conv_kvin(const float* __restrict__ x,
                                                 const float* __restrict__ lat,
                                                 u16* __restrict__ kvin) {
  const int64_t total8 = (int64_t)20480 * 1024 / 8;
  for (int64_t i = (int64_t)blockIdx.x * 256 + threadIdx.x; i < total8;
       i += (int64_t)gridDim.x * 256) {
    const int64_t e0 = i * 8;
    const int row = (int)(e0 >> 10);
    const int col = (int)(e0 & 1023);
    const int b = row / 2560;
    const int t = row - b * 2560;
    const float* src = (t < 2048)
        ? (x + ((int64_t)b * 2048 + t) * 1024 + col)
        : (lat + ((int64_t)b * 512 + (t - 2048)) * 1024 + col);
    const float4 v0 = *(const float4*)src;
    const float4 v1 = *(const float4*)(src + 4);
    union { u16 s[8]; short8 v; } pk;
    pk.s[0] = f2bf(v0.x); pk.s[1] = f2bf(v0.y); pk.s[2] = f2bf(v0.z); pk.s[3] = f2bf(v0.w);
    pk.s[4] = f2bf(v1.x); pk.s[5] = f2bf(v1.y); pk.s[6] = f2bf(v1.z); pk.s[7] = f2bf(v1.w);
    *(short8*)(kvin + e0) = pk.v;
  }
}

// ---------- mask -> additive bias over concatenated kv timeline ----------
__global__ __launch_bounds__(256) void prep_bias(const float* __restrict__ mask_x,
                                                 const float* __restrict__ mask_lat,
                                                 float* __restrict__ biasKV) {
  const int i = blockIdx.x * 256 + threadIdx.x;  // < 20480
  if (i >= 20480) return;
  const int b = i / 2560, t = i - b * 2560;
  const float m = (t < 2048) ? mask_x[b * 2048 + t] : mask_lat[b * 512 + t - 2048];
  biasKV[i] = (1.0f - m) * (-1.0e30f);
}

// ---------- transpose + convert weights: dst[n][k] = bf16(src[k][n]) ----------
__global__ __launch_bounds__(256) void convT(const float* __restrict__ src,
                                             u16* __restrict__ dst, int K, int N) {
  __shared__ float tile[32][33];
  const int kb = blockIdx.x * 32, nb = blockIdx.y * 32;
  const int tx = threadIdx.x & 31, ty = threadIdx.x >> 5;
  #pragma unroll
  for (int i = 0; i < 4; i++)
    tile[ty + i * 8][tx] = src[(int64_t)(kb + ty + i * 8) * N + nb + tx];
  __syncthreads();
  #pragma unroll
  for (int i = 0; i < 4; i++)
    dst[(int64_t)(nb + ty + i * 8) * K + kb + tx] = f2bf(tile[tx][ty + i * 8]);
}

// ---------- 128x128 bf16 MFMA GEMM, K=1024, B given as Bt[N][K] ----------
// LDS tiles XOR-swizzled (T2): staging sources the inverse-permuted global slot
// (ss^sr involution within each 8-row chunk, linear LDS dest per rule 21);
// fragment reads XOR the 16B-slot with row&7 -> 2-way bank aliasing (free).
// MODE 0: q-GEMM   (A rows = latent part of kvin; out bf16 * 0.125*log2e for exp2-domain softmax)
// MODE 1: kv-GEMM  (out col<1024 -> kbuf row-major bf16; col>=1024 -> vT transposed bf16)
// MODE 2: out-GEMM (A already bf16 flat, out fp32)
template <int MODE>
__global__ __launch_bounds__(256) void gemm128(const u16* __restrict__ A0,
                                               const u16* __restrict__ Bt,
                                               void* __restrict__ C0,
                                               void* __restrict__ C1) {
  __shared__ u16 As[128 * 64];
  __shared__ u16 Bs[128 * 64];
  const int tid = threadIdx.x;
  const int lane = tid & 63, wave = tid >> 6;
  const int l16 = lane & 15, g4 = lane >> 4;
  const int bm = blockIdx.x, bn = blockIdx.y;

  const u16* Arow;
  if (MODE == 0) {
    const int b = bm >> 2;
    Arow = A0 + ((int64_t)b * 2560 + 2048 + (int64_t)(bm & 3) * 128) * 1024;
  } else {
    Arow = A0 + (int64_t)bm * 128 * 1024;
  }
  const u16* Brow = Bt + (int64_t)bn * 128 * 1024;

  const int wm = wave >> 1, wn = wave & 1;
  const int sr = lane >> 3;              // row within 8-row staging chunk
  const int ss = lane & 7;               // 16B slot within 128B row
  const int swslot = (ss ^ sr) * 8;      // inverse-swizzled source offset (u16)

  f32x4 acc[4][4];
  #pragma unroll
  for (int m = 0; m < 4; m++)
    #pragma unroll
    for (int n = 0; n < 4; n++)
      acc[m][n] = (f32x4){0.f, 0.f, 0.f, 0.f};

  for (int kt = 0; kt < 1024; kt += 64) {
    #pragma unroll
    for (int i = 0; i < 4; i++) {
      const int c = wave * 4 + i;
      gl2lds16(Arow + (int64_t)(c * 8 + sr) * 1024 + kt + swslot, &As[c * 512]);
      gl2lds16(Brow + (int64_t)(c * 8 + sr) * 1024 + kt + swslot, &Bs[c * 512]);
    }
    __syncthreads();
    #pragma unroll
    for (int kk = 0; kk < 2; kk++) {
      short8 af[4], bfr[4];
      #pragma unroll
      for (int m = 0; m < 4; m++)
        af[m] = *(const short8*)&As[(wm * 64 + m * 16 + l16) * 64 +
                                    (((kk * 4 + g4) ^ (l16 & 7)) * 8)];
      #pragma unroll
      for (int n = 0; n < 4; n++)
        bfr[n] = *(const short8*)&Bs[(wn * 64 + n * 16 + l16) * 64 +
                                     (((kk * 4 + g4) ^ (l16 & 7)) * 8)];
      #pragma unroll
      for (int m = 0; m < 4; m++)
        #pragma unroll
        for (int n = 0; n < 4; n++)
          acc[m][n] = __builtin_amdgcn_mfma_f32_16x16x32_bf16(af[m], bfr[n], acc[m][n], 0, 0, 0);
    }
    __syncthreads();
  }

  const int g4e = lane >> 4;
  const int r0 = bm * 128 + wm * 64;
  const int c0 = bn * 128 + wn * 64;
  #pragma unroll
  for (int m = 0; m < 4; m++) {
    #pragma unroll
    for (int n = 0; n < 4; n++) {
      const int col = c0 + n * 16 + l16;
      if (MODE == 1 && col >= 1024) {
        const int rbase = r0 + m * 16 + g4e * 4;
        const int b = rbase / 2560;
        const int t = rbase - b * 2560;
        u16x4 vv;
        vv[0] = f2bf(acc[m][n][0]); vv[1] = f2bf(acc[m][n][1]);
        vv[2] = f2bf(acc[m][n][2]); vv[3] = f2bf(acc[m][n][3]);
        *(u16x4*)((u16*)C1 + ((int64_t)b * 1024 + (col - 1024)) * 2560 + t) = vv;
      } else {
        #pragma unroll
        for (int j = 0; j < 4; j++) {
          const int row = r0 + m * 16 + g4e * 4 + j;
          const float v = acc[m][n][j];
          if (MODE == 2)      ((float*)C0)[(int64_t)row * 1024 + col] = v;
          else if (MODE == 0) ((u16*)C0)[(int64_t)row * 1024 + col] = f2bf(v * 0.18033688f);
          else                ((u16*)C0)[(int64_t)row * 1024 + col] = f2bf(v);
        }
      }
    }
  }
}

// ---------- flash attention v5: block = 128 q-rows, K/V LDS-staged (coalesced + swizzled) ----------
// 4 waves x 32 q-rows each; all waves share double-buffered K/V tiles (64 kv-rows x 64d).
// Staging: linear LDS dest via global_load_lds, INVERSE-swizzled global source; reads apply the
// same slot XOR (s ^ (row&7)) -> <=4-way bank aliasing. One barrier per tile. No merge phase.
__global__ __launch_bounds__(256, 2) void attn5(const u16* __restrict__ q,
                                                const u16* __restrict__ kbuf,
                                                const u16* __restrict__ vT,
                                                const float* __restrict__ biasKV,
                                                u16* __restrict__ y) {
  __shared__ u16 Klds[2][64][64];  // [buf][t-row][d], 8KB each
  __shared__ u16 Vlds[2][64][64];  // [buf][d-row][t], 8KB each

  // bijective XCD swizzle over 512 blocks: same (b,h) -> same XCD
  const int id = blockIdx.x;                // 0..511
  const int xcd = id & 7, rest = id >> 3;   // rest 0..63
  const int bh = xcd * 16 + (rest >> 2);    // 0..127
  const int qb = rest & 3;                  // 0..3
  const int b = bh >> 4, h = bh & 15;
  const int lane = threadIdx.x & 63, wave = threadIdx.x >> 6;
  const int l32 = lane & 31, hi = lane >> 5;
  const int q0 = qb * 128 + wave * 32;

  const u16* kg = kbuf + (int64_t)(b * 2560) * 1024 + h * 64;  // row t stride 1024
  const u16* vg = vT + ((int64_t)(b * 1024 + h * 64)) * 2560;  // row d stride 2560
  const float* bbase = biasKV + b * 2560;

  // Q^T B-fragments: col q = l32, d = c*16 + hi*8 + j (scattered, loaded once)
  short8 qf[4];
  const u16* qrow = q + ((int64_t)(b * 512 + q0 + l32)) * 1024 + h * 64;
  #pragma unroll
  for (int c = 0; c < 4; c++)
    qf[c] = *(const short8*)(qrow + c * 16 + hi * 8);

  float mrun = -3.0e38f, lsum = 0.f;
  f32x16 yacc0, yacc1;
  #pragma unroll
  for (int i = 0; i < 16; i++) { yacc0[i] = 0.f; yacc1[i] = 0.f; }

  const int sr = lane >> 3;  // 0..7: row within an 8-row staging chunk
  const int ss = lane & 7;   // 0..7: 16B slot within a 128B row
  const int swslot = (ss ^ sr) * 8;  // inverse-swizzled source offset (u16)

  // prologue: stage tile 0 into buf 0
  #pragma unroll
  for (int j = 0; j < 2; j++) {
    const int r = wave * 16 + j * 8 + sr;
    gl2lds16(kg + (int64_t)r * 1024 + swslot, &Klds[0][wave * 16 + j * 8][0]);
    gl2lds16(vg + (int64_t)r * 2560 + swslot, &Vlds[0][wave * 16 + j * 8][0]);
  }
  __syncthreads();

  int cur = 0;
  for (int tile = 0; tile < 40; ++tile) {
    const int T0 = tile * 64;
    if (tile + 1 < 40) {  // stage next tile into the other buffer (drained at the barrier)
      const int nb = cur ^ 1, T1 = T0 + 64;
      #pragma unroll
      for (int j = 0; j < 2; j++) {
        const int r = wave * 16 + j * 8 + sr;
        gl2lds16(kg + (int64_t)(T1 + r) * 1024 + swslot, &Klds[nb][wave * 16 + j * 8][0]);
        gl2lds16(vg + (int64_t)r * 2560 + T1 + swslot, &Vlds[nb][wave * 16 + j * 8][0]);
      }
    }

    #pragma unroll
    for (int ht = 0; ht < 2; ++ht) {
      const int t0h = T0 + ht * 32;
      // K A-fragments from LDS: row = ht*32 + l32, slot (c*2+hi) ^ (l32&7)
      short8 kf[4];
      #pragma unroll
      for (int c = 0; c < 4; c++)
        kf[c] = *(const short8*)&Klds[cur][ht * 32 + l32][((c * 2 + hi) ^ (l32 & 7)) * 8];
      // V^T A-fragments from LDS: d-row = db*32 + l32, slot (ht*4+ks*2+hi) ^ (l32&7)
      short8 vf[2][2];
      #pragma unroll
      for (int db = 0; db < 2; db++)
        #pragma unroll
        for (int ks = 0; ks < 2; ks++)
          vf[db][ks] = *(const short8*)&Vlds[cur][db * 32 + l32]
                                            [((ht * 4 + ks * 2 + hi) ^ (l32 & 7)) * 8];
      // mask bias, float4 per reg-group g: t = t0h + g*8 + 4*hi + (r&3)
      float4 bb[4];
      #pragma unroll
      for (int g = 0; g < 4; g++)
        bb[g] = *(const float4*)(bbase + t0h + g * 8 + hi * 4);

      // S^T[k][q] = sum_d K[k][d] * Q^T[d][q]
      f32x16 S;
      #pragma unroll
      for (int i = 0; i < 16; i++) S[i] = 0.f;
      #pragma unroll
      for (int c = 0; c < 4; c++)
        S = __builtin_amdgcn_mfma_f32_32x32x16_bf16(kf[c], qf[c], S, 0, 0, 0);

      float t[16];
      #pragma unroll
      for (int r = 0; r < 16; r++) t[r] = S[r] + bb[r >> 2][r & 3];

      // row max: in-register tree + one cross-half swap
      float m01 = fmaxf(t[0], t[1]),  m23 = fmaxf(t[2], t[3]);
      float m45 = fmaxf(t[4], t[5]),  m67 = fmaxf(t[6], t[7]);
      float m89 = fmaxf(t[8], t[9]),  mab = fmaxf(t[10], t[11]);
      float mcd = fmaxf(t[12], t[13]), mef = fmaxf(t[14], t[15]);
      float tm = fmaxf(fmaxf(fmaxf(m01, m23), fmaxf(m45, m67)),
                       fmaxf(fmaxf(m89, mab), fmaxf(mcd, mef)));
      tm = halfmax(tm);

      // defer-max: rescale only when the running max grew past threshold (log2 units)
      if (__any(tm > mrun + 8.f)) {
        const float nm = fmaxf(mrun, tm);
        const float alpha = exp2fast(mrun - nm);
        mrun = nm;
        lsum *= alpha;
        #pragma unroll
        for (int i = 0; i < 16; i++) { yacc0[i] *= alpha; yacc1[i] *= alpha; }
      }

      float p[16];
      #pragma unroll
      for (int r = 0; r < 16; r++) p[r] = exp2fast(t[r] - mrun);

      float ps = ((p[0] + p[1]) + (p[2] + p[3])) + ((p[4] + p[5]) + (p[6] + p[7]));
      ps += ((p[8] + p[9]) + (p[10] + p[11])) + ((p[12] + p[13]) + (p[14] + p[15]));
      lsum += halfadd(ps);

      // P^T B-fragments via cvt_pk + permlane32_swap (T12)
      union PA { unsigned int w[4]; short8 v; } pa0, pa1;
      {
        auto r0 = __builtin_amdgcn_permlane32_swap(cvtpk(p[0], p[1]), cvtpk(p[4], p[5]), false, false);
        pa0.w[0] = r0[0]; pa0.w[2] = r0[1];
        auto r1 = __builtin_amdgcn_permlane32_swap(cvtpk(p[2], p[3]), cvtpk(p[6], p[7]), false, false);
        pa0.w[1] = r1[0]; pa0.w[3] = r1[1];
        auto r2 = __builtin_amdgcn_permlane32_swap(cvtpk(p[8], p[9]), cvtpk(p[12], p[13]), false, false);
        pa1.w[0] = r2[0]; pa1.w[2] = r2[1];
        auto r3 = __builtin_amdgcn_permlane32_swap(cvtpk(p[10], p[11]), cvtpk(p[14], p[15]), false, false);
        pa1.w[1] = r3[0]; pa1.w[3] = r3[1];
      }

      // Y^T[d][q] += V^T[d][k] * P^T[k][q]
      yacc0 = __builtin_amdgcn_mfma_f32_32x32x16_bf16(vf[0][0], pa0.v, yacc0, 0, 0, 0);
      yacc0 = __builtin_amdgcn_mfma_f32_32x32x16_bf16(vf[0][1], pa1.v, yacc0, 0, 0, 0);
      yacc1 = __builtin_amdgcn_mfma_f32_32x32x16_bf16(vf[1][0], pa0.v, yacc1, 0, 0, 0);
      yacc1 = __builtin_amdgcn_mfma_f32_32x32x16_bf16(vf[1][1], pa1.v, yacc1, 0, 0, 0);
    }

    __syncthreads();  // drains staging vmcnt; protects cur from overwrite next iter
    cur ^= 1;
  }

  const float inv = 1.0f / lsum;
  u16* yr = y + ((int64_t)(b * 512 + q0 + l32)) * 1024 + h * 64;
  #pragma unroll
  for (int g = 0; g < 4; g++) {
    u16x4 o0, o1;
    #pragma unroll
    for (int j = 0; j < 4; j++) {
      o0[j] = f2bf(yacc0[g * 4 + j] * inv);
      o1[j] = f2bf(yacc1[g * 4 + j] * inv);
    }
    *(u16x4*)(yr + g * 8 + hi * 4) = o0;
    *(u16x4*)(yr + 32 + g * 8 + hi * 4) = o1;
  }
}

extern "C" void kernel_launch(void* const* d_in, const int* in_sizes, int n_in,
                              void* d_out, int out_size, void* d_ws, size_t ws_size,
                              hipStream_t stream) {
  const float* x        = (const float*)d_in[0];
  const float* lat      = (const float*)d_in[1];
  const float* mask_x   = (const float*)d_in[2];
  const float* mask_lat = (const float*)d_in[3];
  const float* Wq       = (const float*)d_in[4];
  const float* Wkv      = (const float*)d_in[5];
  const float* Wp       = (const float*)d_in[6];

  // workspace carve (bf16 = u16), total ~143 MB
  u16* kvin = (u16*)d_ws;                         // [8][2560][1024]
  u16* WqT  = kvin + (int64_t)20480 * 1024;       // [1024][1024]
  u16* WkvT = WqT  + (int64_t)1024 * 1024;        // [2048][1024]
  u16* WpT  = WkvT + (int64_t)2048 * 1024;        // [1024][1024]
  u16* qb   = WpT  + (int64_t)1024 * 1024;        // [4096][1024]
  u16* kb   = qb   + (int64_t)4096 * 1024;        // [8*2560][1024]
  u16* vT   = kb   + (int64_t)20480 * 1024;       // [8*1024][2560]
  float* biasKV = (float*)(vT + (int64_t)20480 * 1024);  // [8][2560]
  u16* yb   = kvin;                               // reuse kvin after GEMMs

  conv_kvin<<<2560, 256, 0, stream>>>(x, lat, kvin);
  prep_bias<<<80, 256, 0, stream>>>(mask_x, mask_lat, biasKV);
  convT<<<dim3(32, 32), 256, 0, stream>>>(Wq, WqT, 1024, 1024);
  convT<<<dim3(32, 64), 256, 0, stream>>>(Wkv, WkvT, 1024, 2048);
  convT<<<dim3(32, 32), 256, 0, stream>>>(Wp, WpT, 1024, 1024);

  gemm128<0><<<dim3(32, 8), 256, 0, stream>>>(kvin, WqT, qb, nullptr);
  gemm128<1><<<dim3(160, 16), 256, 0, stream>>>(kvin, WkvT, kb, vT);
  attn5<<<512, 256, 0, stream>>>(qb, kb, vT, biasKV, yb);
  gemm128<2><<<dim3(32, 8), 256, 0, stream>>>(yb, WpT, d_out, nullptr);
}

// Round 9
// 362.491 us; speedup vs baseline: 1.3485x; 1.0076x over previous
//
#include <hip/hip_runtime.h>
#include <stdint.h>

typedef unsigned short u16;
typedef __attribute__((ext_vector_type(8))) short short8;
typedef __attribute__((ext_vector_type(4))) float f32x4;
typedef __attribute__((ext_vector_type(16))) float f32x16;
typedef __attribute__((ext_vector_type(4))) unsigned short u16x4;

__device__ __forceinline__ u16 f2bf(float f) {
  uint32_t u = __float_as_uint(f);
  return (u16)((u + 0x7FFFu + ((u >> 16) & 1u)) >> 16);
}

__device__ __forceinline__ void gl2lds16(const u16* g, u16* l) {
  __builtin_amdgcn_global_load_lds(
      (const __attribute__((address_space(1))) unsigned int*)g,
      (__attribute__((address_space(3))) unsigned int*)l, 16, 0, 0);
}

__device__ __forceinline__ float exp2fast(float x) {
#if __has_builtin(__builtin_amdgcn_exp2f)
  return __builtin_amdgcn_exp2f(x);
#else
  return exp2f(x);
#endif
}

__device__ __forceinline__ unsigned int cvtpk(float lo, float hi) {
  unsigned int r;
  asm("v_cvt_pk_bf16_f32 %0, %1, %2" : "=v"(r) : "v"(lo), "v"(hi));
  return r;
}

// cross-half (lane vs lane^32) combine helpers via permlane32_swap
__device__ __forceinline__ float halfmax(float x) {
  auto r = __builtin_amdgcn_permlane32_swap(__float_as_uint(x), __float_as_uint(x), false, false);
  return fmaxf(__uint_as_float(r[0]), __uint_as_float(r[1]));
}
__device__ __forceinline__ float halfadd(float x) {
  auto r = __builtin_amdgcn_permlane32_swap(__float_as_uint(x), __float_as_uint(x), false, false);
  return __uint_as_float(r[0]) + __uint_as_float(r[1]);
}

// ---------- convert + concat: kvin[b][t][e] bf16, t<2048 -> x, else latents ----------
__global__ __launch_bounds__(256) void conv_kvin(const float* __restrict__ x,
                                                 const float* __restrict__ lat,
                                                 u16* __restrict__ kvin) {
  const int64_t total8 = (int64_t)20480 * 1024 / 8;
  for (int64_t i = (int64_t)blockIdx.x * 256 + threadIdx.x; i < total8;
       i += (int64_t)gridDim.x * 256) {
    const int64_t e0 = i * 8;
    const int row = (int)(e0 >> 10);
    const int col = (int)(e0 & 1023);
    const int b = row / 2560;
    const int t = row - b * 2560;
    const float* src = (t < 2048)
        ? (x + ((int64_t)b * 2048 + t) * 1024 + col)
        : (lat + ((int64_t)b * 512 + (t - 2048)) * 1024 + col);
    const float4 v0 = *(const float4*)src;
    const float4 v1 = *(const float4*)(src + 4);
    union { u16 s[8]; short8 v; } pk;
    pk.s[0] = f2bf(v0.x); pk.s[1] = f2bf(v0.y); pk.s[2] = f2bf(v0.z); pk.s[3] = f2bf(v0.w);
    pk.s[4] = f2bf(v1.x); pk.s[5] = f2bf(v1.y); pk.s[6] = f2bf(v1.z); pk.s[7] = f2bf(v1.w);
    *(short8*)(kvin + e0) = pk.v;
  }
}

// ---------- mask -> additive bias over concatenated kv timeline ----------
__global__ __launch_bounds__(256) void prep_bias(const float* __restrict__ mask_x,
                                                 const float* __restrict__ mask_lat,
                                                 float* __restrict__ biasKV) {
  const int i = blockIdx.x * 256 + threadIdx.x;  // < 20480
  if (i >= 20480) return;
  const int b = i / 2560, t = i - b * 2560;
  const float m = (t < 2048) ? mask_x[b * 2048 + t] : mask_lat[b * 512 + t - 2048];
  biasKV[i] = (1.0f - m) * (-1.0e30f);
}

// ---------- transpose + convert weights: dst[n][k] = bf16(src[k][n]) ----------
__global__ __launch_bounds__(256) void convT(const float* __restrict__ src,
                                             u16* __restrict__ dst, int K, int N) {
  __shared__ float tile[32][33];
  const int kb = blockIdx.x * 32, nb = blockIdx.y * 32;
  const int tx = threadIdx.x & 31, ty = threadIdx.x >> 5;
  #pragma unroll
  for (int i = 0; i < 4; i++)
    tile[ty + i * 8][tx] = src[(int64_t)(kb + ty + i * 8) * N + nb + tx];
  __syncthreads();
  #pragma unroll
  for (int i = 0; i < 4; i++)
    dst[(int64_t)(nb + ty + i * 8) * K + kb + tx] = f2bf(tile[tx][ty + i * 8]);
}

// ---------- 128x128 bf16 MFMA GEMM (q-GEMM and out-GEMM), K=1024, B as Bt[N][K] ----------
// LDS XOR-swizzled (T2), both-sides-or-neither (rule 21).
// MODE 0: q-GEMM (A rows = latent part of kvin; out bf16 * 0.125*log2e)
// MODE 2: out-GEMM (A bf16 flat, out fp32)
template <int MODE>
__global__ __launch_bounds__(256) void gemm128(const u16* __restrict__ A0,
                                               const u16* __restrict__ Bt,
                                               void* __restrict__ C0) {
  __shared__ u16 As[128 * 64];
  __shared__ u16 Bs[128 * 64];
  const int tid = threadIdx.x;
  const int lane = tid & 63, wave = tid >> 6;
  const int l16 = lane & 15, g4 = lane >> 4;
  const int bm = blockIdx.x, bn = blockIdx.y;

  const u16* Arow;
  if (MODE == 0) {
    const int b = bm >> 2;
    Arow = A0 + ((int64_t)b * 2560 + 2048 + (int64_t)(bm & 3) * 128) * 1024;
  } else {
    Arow = A0 + (int64_t)bm * 128 * 1024;
  }
  const u16* Brow = Bt + (int64_t)bn * 128 * 1024;

  const int wm = wave >> 1, wn = wave & 1;
  const int sr = lane >> 3;
  const int ss = lane & 7;
  const int swslot = (ss ^ sr) * 8;

  f32x4 acc[4][4];
  #pragma unroll
  for (int m = 0; m < 4; m++)
    #pragma unroll
    for (int n = 0; n < 4; n++)
      acc[m][n] = (f32x4){0.f, 0.f, 0.f, 0.f};

  for (int kt = 0; kt < 1024; kt += 64) {
    #pragma unroll
    for (int i = 0; i < 4; i++) {
      const int c = wave * 4 + i;
      gl2lds16(Arow + (int64_t)(c * 8 + sr) * 1024 + kt + swslot, &As[c * 512]);
      gl2lds16(Brow + (int64_t)(c * 8 + sr) * 1024 + kt + swslot, &Bs[c * 512]);
    }
    __syncthreads();
    #pragma unroll
    for (int kk = 0; kk < 2; kk++) {
      short8 af[4], bfr[4];
      #pragma unroll
      for (int m = 0; m < 4; m++)
        af[m] = *(const short8*)&As[(wm * 64 + m * 16 + l16) * 64 +
                                    (((kk * 4 + g4) ^ (l16 & 7)) * 8)];
      #pragma unroll
      for (int n = 0; n < 4; n++)
        bfr[n] = *(const short8*)&Bs[(wn * 64 + n * 16 + l16) * 64 +
                                     (((kk * 4 + g4) ^ (l16 & 7)) * 8)];
      #pragma unroll
      for (int m = 0; m < 4; m++)
        #pragma unroll
        for (int n = 0; n < 4; n++)
          acc[m][n] = __builtin_amdgcn_mfma_f32_16x16x32_bf16(af[m], bfr[n], acc[m][n], 0, 0, 0);
    }
    __syncthreads();
  }

  const int r0 = bm * 128 + wm * 64;
  const int c0 = bn * 128 + wn * 64;
  #pragma unroll
  for (int m = 0; m < 4; m++) {
    #pragma unroll
    for (int n = 0; n < 4; n++) {
      const int col = c0 + n * 16 + l16;
      #pragma unroll
      for (int j = 0; j < 4; j++) {
        const int row = r0 + m * 16 + g4 * 4 + j;
        const float v = acc[m][n][j];
        if (MODE == 2)      ((float*)C0)[(int64_t)row * 1024 + col] = v;
        else                ((u16*)C0)[(int64_t)row * 1024 + col] = f2bf(v * 0.18033688f);
      }
    }
  }
}

// ---------- 256x256 8-phase bf16 GEMM for kv (T2+T3+T4+T5), K=1024 ----------
// 8 waves (2M x 4N), BK=64, LDS 128KB double-buffered. Per K-tile: 4 phases of
// {ds_read quadrant (+B at q0) | issue 2 stage loads for t+1 | barrier |
//  setprio(1) 16xMFMA setprio(0) | barrier}. Counted waits: staging order is
// B c0..c3, A c0,c2, A c1,c3 (needed-first); vmcnt(2)@q0 certifies B+A(c0,c2),
// vmcnt(4)@q2 certifies A(c1,c3) (4 newer loads in flight). Each wait is
// followed by a barrier: every wave certifies ITS OWN staged rows, the barrier
// extends that to all waves. Staging targets the buffer not being read.
// Epilogue: col<1024 -> kb row-major; col>=1024 -> vT[(b*1024+d)][t] transposed.
__global__ __launch_bounds__(512, 2) void gemm256kv(const u16* __restrict__ A0,
                                                    const u16* __restrict__ Bt,
                                                    u16* __restrict__ kb,
                                                    u16* __restrict__ vT) {
  __shared__ u16 As[2][256][64];
  __shared__ u16 Bs[2][256][64];
  const int tid = threadIdx.x;
  const int lane = tid & 63, wave = tid >> 6;      // wave 0..7
  const int l16 = lane & 15, g4 = lane >> 4;
  const int wm = wave >> 2, wn = wave & 3;          // 2M x 4N

  // bijective XCD swizzle over 640 blocks (640%8==0): 80 consecutive per XCD
  const int id = blockIdx.x;
  const int wgid = (id & 7) * 80 + (id >> 3);
  const int bm = wgid >> 3, bn = wgid & 7;          // 80 x 8

  const u16* Arow = A0 + (int64_t)bm * 256 * 1024;
  const u16* Brow = Bt + (int64_t)bn * 256 * 1024;

  const int sr = lane >> 3;             // row within 8-row staging chunk
  const int ss = lane & 7;              // 16B slot within 128B row
  const int swslot = (ss ^ sr) * 8;     // inverse-swizzled source offset (u16)
  const int g8 = wave * 8;              // base row of this wave's chunk-0 group

  f32x4 acc[8][4];
  #pragma unroll
  for (int m = 0; m < 8; m++)
    #pragma unroll
    for (int n = 0; n < 4; n++)
      acc[m][n] = (f32x4){0.f, 0.f, 0.f, 0.f};

  // ---- prologue: stage tile 0 into buf 0, needed-first order ----
  {
    const int kt = 0;
    // B chunks c0..c3 (rows wave*8 + c*64)
    #pragma unroll
    for (int c = 0; c < 4; c++)
      gl2lds16(Brow + (int64_t)(c * 64 + g8 + sr) * 1024 + kt + swslot, &Bs[0][c * 64 + g8][0]);
    // A chunks c0, c2, c1, c3
    gl2lds16(Arow + (int64_t)(0 * 64 + g8 + sr) * 1024 + kt + swslot, &As[0][0 * 64 + g8][0]);
    gl2lds16(Arow + (int64_t)(2 * 64 + g8 + sr) * 1024 + kt + swslot, &As[0][2 * 64 + g8][0]);
    gl2lds16(Arow + (int64_t)(1 * 64 + g8 + sr) * 1024 + kt + swslot, &As[0][1 * 64 + g8][0]);
    gl2lds16(Arow + (int64_t)(3 * 64 + g8 + sr) * 1024 + kt + swslot, &As[0][3 * 64 + g8][0]);
  }

  for (int t = 0; t < 16; ++t) {
    const int buf = t & 1, nb = buf ^ 1;
    const int ktn = (t + 1) * 64;
    const bool more = (t + 1 < 16);
    short8 bf[4][2];

    #pragma unroll
    for (int q = 0; q < 4; ++q) {
      if (q == 0) {
        asm volatile("s_waitcnt vmcnt(2)" ::: "memory");
        __builtin_amdgcn_s_barrier();
      }
      if (q == 2) {
        if (more) asm volatile("s_waitcnt vmcnt(4)" ::: "memory");
        else      asm volatile("s_waitcnt vmcnt(0)" ::: "memory");
        __builtin_amdgcn_s_barrier();
      }

      // ds-read register subtile
      if (q == 0) {
        #pragma unroll
        for (int n = 0; n < 4; n++)
          #pragma unroll
          for (int kk = 0; kk < 2; kk++)
            bf[n][kk] = *(const short8*)&Bs[buf][wn * 64 + n * 16 + l16]
                                            [((kk * 4 + g4) ^ (l16 & 7)) * 8];
      }
      short8 af[2][2];
      #pragma unroll
      for (int m2 = 0; m2 < 2; m2++)
        #pragma unroll
        for (int kk = 0; kk < 2; kk++)
          af[m2][kk] = *(const short8*)&As[buf][wm * 128 + (q * 2 + m2) * 16 + l16]
                                          [((kk * 4 + g4) ^ (l16 & 7)) * 8];

      // stage 2 half-tiles of tile t+1 (needed-first order across phases)
      if (more) {
        if (q == 0) {
          gl2lds16(Brow + (int64_t)(0 * 64 + g8 + sr) * 1024 + ktn + swslot, &Bs[nb][0 * 64 + g8][0]);
          gl2lds16(Brow + (int64_t)(1 * 64 + g8 + sr) * 1024 + ktn + swslot, &Bs[nb][1 * 64 + g8][0]);
        } else if (q == 1) {
          gl2lds16(Brow + (int64_t)(2 * 64 + g8 + sr) * 1024 + ktn + swslot, &Bs[nb][2 * 64 + g8][0]);
          gl2lds16(Brow + (int64_t)(3 * 64 + g8 + sr) * 1024 + ktn + swslot, &Bs[nb][3 * 64 + g8][0]);
        } else if (q == 2) {
          gl2lds16(Arow + (int64_t)(0 * 64 + g8 + sr) * 1024 + ktn + swslot, &As[nb][0 * 64 + g8][0]);
          gl2lds16(Arow + (int64_t)(2 * 64 + g8 + sr) * 1024 + ktn + swslot, &As[nb][2 * 64 + g8][0]);
        } else {
          gl2lds16(Arow + (int64_t)(1 * 64 + g8 + sr) * 1024 + ktn + swslot, &As[nb][1 * 64 + g8][0]);
          gl2lds16(Arow + (int64_t)(3 * 64 + g8 + sr) * 1024 + ktn + swslot, &As[nb][3 * 64 + g8][0]);
        }
      }

      __builtin_amdgcn_s_barrier();
      __builtin_amdgcn_s_setprio(1);
      #pragma unroll
      for (int m2 = 0; m2 < 2; m2++)
        #pragma unroll
        for (int n = 0; n < 4; n++)
          #pragma unroll
          for (int kk = 0; kk < 2; kk++)
            acc[q * 2 + m2][n] = __builtin_amdgcn_mfma_f32_16x16x32_bf16(
                af[m2][kk], bf[n][kk], acc[q * 2 + m2][n], 0, 0, 0);
      __builtin_amdgcn_s_setprio(0);
      __builtin_amdgcn_s_barrier();
    }
  }

  // ---- epilogue: K part row-major, V part transposed ----
  const int r0 = bm * 256 + wm * 128;
  const int c0 = bn * 256 + wn * 64;
  #pragma unroll
  for (int m = 0; m < 8; m++) {
    #pragma unroll
    for (int n = 0; n < 4; n++) {
      const int col = c0 + n * 16 + l16;
      const int rbase = r0 + m * 16 + g4 * 4;
      if (col >= 1024) {
        const int b = rbase / 2560;
        const int t = rbase - b * 2560;
        u16x4 vv;
        vv[0] = f2bf(acc[m][n][0]); vv[1] = f2bf(acc[m][n][1]);
        vv[2] = f2bf(acc[m][n][2]); vv[3] = f2bf(acc[m][n][3]);
        *(u16x4*)(vT + ((int64_t)b * 1024 + (col - 1024)) * 2560 + t) = vv;
      } else {
        #pragma unroll
        for (int j = 0; j < 4; j++)
          kb[(int64_t)(rbase + j) * 1024 + col] = f2bf(acc[m][n][j]);
      }
    }
  }
}

// ---------- flash attention v5: block = 128 q-rows, K/V LDS-staged (coalesced + swizzled) ----------
__global__ __launch_bounds__(256, 2) void attn5(const u16* __restrict__ q,
                                                const u16* __restrict__ kbuf,
                                                const u16* __restrict__ vT,
                                                const float* __restrict__ biasKV,
                                                u16* __restrict__ y) {
  __shared__ u16 Klds[2][64][64];  // [buf][t-row][d], 8KB each
  __shared__ u16 Vlds[2][64][64];  // [buf][d-row][t], 8KB each

  // bijective XCD swizzle over 512 blocks: same (b,h) -> same XCD
  const int id = blockIdx.x;                // 0..511
  const int xcd = id & 7, rest = id >> 3;   // rest 0..63
  const int bh = xcd * 16 + (rest >> 2);    // 0..127
  const int qb = rest & 3;                  // 0..3
  const int b = bh >> 4, h = bh & 15;
  const int lane = threadIdx.x & 63, wave = threadIdx.x >> 6;
  const int l32 = lane & 31, hi = lane >> 5;
  const int q0 = qb * 128 + wave * 32;

  const u16* kg = kbuf + (int64_t)(b * 2560) * 1024 + h * 64;  // row t stride 1024
  const u16* vg = vT + ((int64_t)(b * 1024 + h * 64)) * 2560;  // row d stride 2560
  const float* bbase = biasKV + b * 2560;

  // Q^T B-fragments: col q = l32, d = c*16 + hi*8 + j (scattered, loaded once)
  short8 qf[4];
  const u16* qrow = q + ((int64_t)(b * 512 + q0 + l32)) * 1024 + h * 64;
  #pragma unroll
  for (int c = 0; c < 4; c++)
    qf[c] = *(const short8*)(qrow + c * 16 + hi * 8);

  float mrun = -3.0e38f, lsum = 0.f;
  f32x16 yacc0, yacc1;
  #pragma unroll
  for (int i = 0; i < 16; i++) { yacc0[i] = 0.f; yacc1[i] = 0.f; }

  const int sr = lane >> 3;  // 0..7: row within an 8-row staging chunk
  const int ss = lane & 7;   // 0..7: 16B slot within a 128B row
  const int swslot = (ss ^ sr) * 8;  // inverse-swizzled source offset (u16)

  // prologue: stage tile 0 into buf 0
  #pragma unroll
  for (int j = 0; j < 2; j++) {
    const int r = wave * 16 + j * 8 + sr;
    gl2lds16(kg + (int64_t)r * 1024 + swslot, &Klds[0][wave * 16 + j * 8][0]);
    gl2lds16(vg + (int64_t)r * 2560 + swslot, &Vlds[0][wave * 16 + j * 8][0]);
  }
  __syncthreads();

  int cur = 0;
  for (int tile = 0; tile < 40; ++tile) {
    const int T0 = tile * 64;
    if (tile + 1 < 40) {  // stage next tile into the other buffer (drained at the barrier)
      const int nb = cur ^ 1, T1 = T0 + 64;
      #pragma unroll
      for (int j = 0; j < 2; j++) {
        const int r = wave * 16 + j * 8 + sr;
        gl2lds16(kg + (int64_t)(T1 + r) * 1024 + swslot, &Klds[nb][wave * 16 + j * 8][0]);
        gl2lds16(vg + (int64_t)r * 2560 + T1 + swslot, &Vlds[nb][wave * 16 + j * 8][0]);
      }
    }

    #pragma unroll
    for (int ht = 0; ht < 2; ++ht) {
      const int t0h = T0 + ht * 32;
      // K A-fragments from LDS: row = ht*32 + l32, slot (c*2+hi) ^ (l32&7)
      short8 kf[4];
      #pragma unroll
      for (int c = 0; c < 4; c++)
        kf[c] = *(const short8*)&Klds[cur][ht * 32 + l32][((c * 2 + hi) ^ (l32 & 7)) * 8];
      // V^T A-fragments from LDS: d-row = db*32 + l32, slot (ht*4+ks*2+hi) ^ (l32&7)
      short8 vf[2][2];
      #pragma unroll
      for (int db = 0; db < 2; db++)
        #pragma unroll
        for (int ks = 0; ks < 2; ks++)
          vf[db][ks] = *(const short8*)&Vlds[cur][db * 32 + l32]
                                            [((ht * 4 + ks * 2 + hi) ^ (l32 & 7)) * 8];
      // mask bias, float4 per reg-group g: t = t0h + g*8 + 4*hi + (r&3)
      float4 bb[4];
      #pragma unroll
      for (int g = 0; g < 4; g++)
        bb[g] = *(const float4*)(bbase + t0h + g * 8 + hi * 4);

      // S^T[k][q] = sum_d K[k][d] * Q^T[d][q]
      f32x16 S;
      #pragma unroll
      for (int i = 0; i < 16; i++) S[i] = 0.f;
      #pragma unroll
      for (int c = 0; c < 4; c++)
        S = __builtin_amdgcn_mfma_f32_32x32x16_bf16(kf[c], qf[c], S, 0, 0, 0);

      float t[16];
      #pragma unroll
      for (int r = 0; r < 16; r++) t[r] = S[r] + bb[r >> 2][r & 3];

      // row max: in-register tree + one cross-half swap
      float m01 = fmaxf(t[0], t[1]),  m23 = fmaxf(t[2], t[3]);
      float m45 = fmaxf(t[4], t[5]),  m67 = fmaxf(t[6], t[7]);
      float m89 = fmaxf(t[8], t[9]),  mab = fmaxf(t[10], t[11]);
      float mcd = fmaxf(t[12], t[13]), mef = fmaxf(t[14], t[15]);
      float tm = fmaxf(fmaxf(fmaxf(m01, m23), fmaxf(m45, m67)),
                       fmaxf(fmaxf(m89, mab), fmaxf(mcd, mef)));
      tm = halfmax(tm);

      // defer-max: rescale only when the running max grew past threshold (log2 units)
      if (__any(tm > mrun + 8.f)) {
        const float nm = fmaxf(mrun, tm);
        const float alpha = exp2fast(mrun - nm);
        mrun = nm;
        lsum *= alpha;
        #pragma unroll
        for (int i = 0; i < 16; i++) { yacc0[i] *= alpha; yacc1[i] *= alpha; }
      }

      float p[16];
      #pragma unroll
      for (int r = 0; r < 16; r++) p[r] = exp2fast(t[r] - mrun);

      float ps = ((p[0] + p[1]) + (p[2] + p[3])) + ((p[4] + p[5]) + (p[6] + p[7]));
      ps += ((p[8] + p[9]) + (p[10] + p[11])) + ((p[12] + p[13]) + (p[14] + p[15]));
      lsum += halfadd(ps);

      // P^T B-fragments via cvt_pk + permlane32_swap (T12)
      union PA { unsigned int w[4]; short8 v; } pa0, pa1;
      {
        auto r0 = __builtin_amdgcn_permlane32_swap(cvtpk(p[0], p[1]), cvtpk(p[4], p[5]), false, false);
        pa0.w[0] = r0[0]; pa0.w[2] = r0[1];
        auto r1 = __builtin_amdgcn_permlane32_swap(cvtpk(p[2], p[3]), cvtpk(p[6], p[7]), false, false);
        pa0.w[1] = r1[0]; pa0.w[3] = r1[1];
        auto r2 = __builtin_amdgcn_permlane32_swap(cvtpk(p[8], p[9]), cvtpk(p[12], p[13]), false, false);
        pa1.w[0] = r2[0]; pa1.w[2] = r2[1];
        auto r3 = __builtin_amdgcn_permlane32_swap(cvtpk(p[10], p[11]), cvtpk(p[14], p[15]), false, false);
        pa1.w[1] = r3[0]; pa1.w[3] = r3[1];
      }

      // Y^T[d][q] += V^T[d][k] * P^T[k][q]
      yacc0 = __builtin_amdgcn_mfma_f32_32x32x16_bf16(vf[0][0], pa0.v, yacc0, 0, 0, 0);
      yacc0 = __builtin_amdgcn_mfma_f32_32x32x16_bf16(vf[0][1], pa1.v, yacc0, 0, 0, 0);
      yacc1 = __builtin_amdgcn_mfma_f32_32x32x16_bf16(vf[1][0], pa0.v, yacc1, 0, 0, 0);
      yacc1 = __builtin_amdgcn_mfma_f32_32x32x16_bf16(vf[1][1], pa1.v, yacc1, 0, 0, 0);
    }

    __syncthreads();  // drains staging vmcnt; protects cur from overwrite next iter
    cur ^= 1;
  }

  const float inv = 1.0f / lsum;
  u16* yr = y + ((int64_t)(b * 512 + q0 + l32)) * 1024 + h * 64;
  #pragma unroll
  for (int g = 0; g < 4; g++) {
    u16x4 o0, o1;
    #pragma unroll
    for (int j = 0; j < 4; j++) {
      o0[j] = f2bf(yacc0[g * 4 + j] * inv);
      o1[j] = f2bf(yacc1[g * 4 + j] * inv);
    }
    *(u16x4*)(yr + g * 8 + hi * 4) = o0;
    *(u16x4*)(yr + 32 + g * 8 + hi * 4) = o1;
  }
}

extern "C" void kernel_launch(void* const* d_in, const int* in_sizes, int n_in,
                              void* d_out, int out_size, void* d_ws, size_t ws_size,
                              hipStream_t stream) {
  const float* x        = (const float*)d_in[0];
  const float* lat      = (const float*)d_in[1];
  const float* mask_x   = (const float*)d_in[2];
  const float* mask_lat = (const float*)d_in[3];
  const float* Wq       = (const float*)d_in[4];
  const float* Wkv      = (const float*)d_in[5];
  const float* Wp       = (const float*)d_in[6];

  // workspace carve (bf16 = u16), total ~143 MB
  u16* kvin = (u16*)d_ws;                         // [8][2560][1024]
  u16* WqT  = kvin + (int64_t)20480 * 1024;       // [1024][1024]
  u16* WkvT = WqT  + (int64_t)1024 * 1024;        // [2048][1024]
  u16* WpT  = WkvT + (int64_t)2048 * 1024;        // [1024][1024]
  u16* qb   = WpT  + (int64_t)1024 * 1024;        // [4096][1024]
  u16* kb   = qb   + (int64_t)4096 * 1024;        // [8*2560][1024]
  u16* vT   = kb   + (int64_t)20480 * 1024;       // [8*1024][2560]
  float* biasKV = (float*)(vT + (int64_t)20480 * 1024);  // [8][2560]
  u16* yb   = kvin;                               // reuse kvin after GEMMs

  conv_kvin<<<2560, 256, 0, stream>>>(x, lat, kvin);
  prep_bias<<<80, 256, 0, stream>>>(mask_x, mask_lat, biasKV);
  convT<<<dim3(32, 32), 256, 0, stream>>>(Wq, WqT, 1024, 1024);
  convT<<<dim3(32, 64), 256, 0, stream>>>(Wkv, WkvT, 1024, 2048);
  convT<<<dim3(32, 32), 256, 0, stream>>>(Wp, WpT, 1024, 1024);

  gemm128<0><<<dim3(32, 8), 256, 0, stream>>>(kvin, WqT, qb);
  gemm256kv<<<640, 512, 0, stream>>>(kvin, WkvT, kb, vT);
  attn5<<<512, 256, 0, stream>>>(qb, kb, vT, biasKV, yb);
  gemm128<2><<<dim3(32, 8), 256, 0, stream>>>(yb, WpT, d_out);
}